// Round 3
// baseline (693.480 us; speedup 1.0000x reference)
//
#include <hip/hip_runtime.h>
#include <hip/hip_bf16.h>
#include <hip/hip_cooperative_groups.h>
#include <math.h>

namespace cg = cooperative_groups;

// ---------------------------------------------------------------------------
// Graft_StackedDense:
//   W0 = blend(w0, g0, p0)  [512,1024]   W1 = blend(w1, g1, p1)  [1,512]
//   out = relu(x @ W0^T + b0) @ W1^T + b1,  x:[65536,1024] fp32
//
// R2: (a) ONE cooperative prep kernel (init/minmax/hist/entropy/blend1/blend0)
//     (b) main MFMA kernel: M-tile 64 x full N=512 per block -> x read ONCE;
//         B staged via global_load_lds w/ 2-way swizzle; fused GEMV epilogue
//         via LDS cross-wave reduction, direct out stores (no atomics).
// ---------------------------------------------------------------------------

typedef __attribute__((ext_vector_type(8))) short short8;
typedef __attribute__((ext_vector_type(4))) float floatx4;
typedef unsigned short ushort_t;

#define WS_ENT 0
#define WS_MM 4
#define WS_CNT 16
#define WS_W0B_WORD 64                // bf16 W0b: 512*1024 shorts = 262144 words
#define WS_W1B_WORD (64 + 262144)     // float W1b[512]

__device__ __forceinline__ unsigned f2ord(float f) {
    unsigned u = __float_as_uint(f);
    return (u & 0x80000000u) ? ~u : (u | 0x80000000u);
}
__device__ __forceinline__ float ord2f(unsigned k) {
    unsigned u = (k & 0x80000000u) ? (k ^ 0x80000000u) : ~k;
    return __uint_as_float(u);
}
__device__ __forceinline__ short f2bf(float f) {
    union { __hip_bfloat16 h; short s; } u;
    u.h = __float2bfloat16(f);
    return u.s;
}
__device__ __forceinline__ float blend_factor(float d, float wg) {
    float wl = 1.0f / (1.0f + expf(-d));
    float wb = wg * (1.0f - expf(-wg * wl));
    float wgr = (1.0f - wg) * (1.0f - expf(-(1.0f - wg) * (1.0f - wl)));
    return 1.0f / (1.0f + expf(-(wb - wgr)));
}
__device__ __forceinline__ float wglobal_from_ent(float eb, float eg) {
    return 0.12732395447351627f * atanf(500.0f * (eb - eg)) + 0.5f;
}
__device__ __forceinline__ void async16(const void* g, void* s) {
    __builtin_amdgcn_global_load_lds(
        (const __attribute__((address_space(1))) unsigned int*)g,
        (__attribute__((address_space(3))) unsigned int*)s, 16, 0, 0);
}

__device__ __forceinline__ void array_map(int bx, const float* w0, const float* g0,
                                          const float* w1, const float* g1,
                                          int& a, const float*& arr, int& per, int& start) {
    if (bx < 64) { a = 0; arr = w0; per = 524288 / 64; start = bx * per; }
    else if (bx < 128) { a = 1; arr = g0; per = 524288 / 64; start = (bx - 64) * per; }
    else if (bx == 128) { a = 2; arr = w1; per = 512; start = 0; }
    else { a = 3; arr = g1; per = 512; start = 0; }
}

// ---------------------------------------------------------------------------
// Cooperative prep kernel: 130 blocks x 256 threads.
// phase0 init -> sync -> phase1 minmax -> sync -> phase2 hist -> sync ->
// phase3 entropy -> sync -> phase4 blend1 (blocks<128) + phase5 blend0.
__global__ __launch_bounds__(256) void prep_kernel(
    const float* __restrict__ w0, const float* __restrict__ g0,
    const float* __restrict__ w1, const float* __restrict__ g1,
    const float* __restrict__ p0, const float* __restrict__ p1,
    unsigned* ws_u, ushort_t* __restrict__ W0bb, float* __restrict__ W1b) {
    cg::grid_group grid = cg::this_grid();
    float* ws_f = (float*)ws_u;
    int bx = blockIdx.x, tid = threadIdx.x;
    int wave = tid >> 6, lane = tid & 63;

    __shared__ float smn[4], smx[4];
    __shared__ float lower[11];
    __shared__ unsigned cnt[10];
    __shared__ float diff[512];
    __shared__ float As[64][17];
    __shared__ float Bs[64][17];

    // ---- phase 0: init ws ----
    if (bx == 0) {
        if (tid < 4) {
            ws_u[WS_MM + 2 * tid] = 0xFFFFFFFFu;
            ws_u[WS_MM + 2 * tid + 1] = 0u;
        }
        if (tid >= WS_CNT && tid < WS_CNT + 40) ws_u[tid] = 0u;
    }
    grid.sync();

    // ---- phase 1: minmax ----
    {
        int a, per, start;
        const float* arr;
        array_map(bx, w0, g0, w1, g1, a, arr, per, start);
        float mn = INFINITY, mx = -INFINITY;
        for (int i = tid; i < per; i += 256) {
            float v = arr[start + i];
            mn = fminf(mn, v);
            mx = fmaxf(mx, v);
        }
#pragma unroll
        for (int off = 32; off > 0; off >>= 1) {
            mn = fminf(mn, __shfl_xor(mn, off));
            mx = fmaxf(mx, __shfl_xor(mx, off));
        }
        if (lane == 0) { smn[wave] = mn; smx[wave] = mx; }
        __syncthreads();
        if (tid == 0) {
            mn = fminf(fminf(smn[0], smn[1]), fminf(smn[2], smn[3]));
            mx = fmaxf(fmaxf(smx[0], smx[1]), fmaxf(smx[2], smx[3]));
            atomicMin(&ws_u[WS_MM + 2 * a], f2ord(mn));
            atomicMax(&ws_u[WS_MM + 2 * a + 1], f2ord(mx));
        }
    }
    grid.sync();

    // ---- phase 2: histogram (exact fp32 boundary arithmetic) ----
    {
        int a, per, start;
        const float* arr;
        array_map(bx, w0, g0, w1, g1, a, arr, per, start);
        float lo = ord2f(ws_u[WS_MM + 2 * a]);
        float hi = ord2f(ws_u[WS_MM + 2 * a + 1]);
        float scale = __fdiv_rn(__fsub_rn(hi, lo), 10.0f);
        if (tid < 11) lower[tid] = __fadd_rn(lo, __fmul_rn((float)tid, scale));
        if (tid < 10) cnt[tid] = 0u;
        __syncthreads();
        float inv_scale = 1.0f / scale;
        for (int i = tid; i < per; i += 256) {
            float v = arr[start + i];
            int g = (int)floorf((v - lo) * inv_scale);
#pragma unroll
            for (int db = -1; db <= 1; db++) {
                int b = g + db;
                if (b >= 0 && b <= 9 && v >= lower[b] && v < lower[b + 1])
                    atomicAdd(&cnt[b], 1u);
            }
        }
        __syncthreads();
        if (tid < 10 && cnt[tid] > 0)
            atomicAdd(&ws_u[WS_CNT + a * 10 + tid], cnt[tid]);
    }
    grid.sync();

    // ---- phase 3: entropy ----
    if (bx == 0 && tid < 4) {
        int a = tid;
        float n = (a < 2) ? 524288.0f : 512.0f;
        float ent = 0.0f;
        for (int i = 0; i < 10; i++) {
            float p = __fdiv_rn((float)ws_u[WS_CNT + a * 10 + i], n);
            if (p > 0.0f) ent = __fsub_rn(ent, __fmul_rn(p, logf(p)));
        }
        ws_f[WS_ENT + a] = ent;
    }
    grid.sync();

    // ---- phase 4: blend1 (blocks 0..127, one output per wave) ----
    if (bx < 128) {
        for (int i = tid; i < 512; i += 256) diff[i] = fabsf(w1[i] - g1[i]);
        __syncthreads();
        int i = bx * 4 + wave;
        float acc = 0.0f;
#pragma unroll
        for (int j = 0; j < 8; j++) {
            int k = lane + 64 * j;
            acc += diff[k] * p1[i * 512 + k];
        }
#pragma unroll
        for (int off = 32; off > 0; off >>= 1) acc += __shfl_xor(acc, off);
        if (lane == 0) {
            float wg = wglobal_from_ent(ws_f[WS_ENT + 2], ws_f[WS_ENT + 3]);
            float s0 = blend_factor(acc, wg);
            W1b[i] = w1[i] * s0 + g1[i] * (1.0f - s0);
        }
        __syncthreads();
    }

    // ---- phase 5: blend0 (blocks 0..127, 64x64 tile each) ----
    if (bx < 128) {
        int bo = (bx >> 4) * 64;   // o in [0,512)
        int bi = (bx & 15) * 64;   // i in [0,1024)
        int tx = tid & 15, ty = tid >> 4;
        int lr = tid >> 2, lc = (tid & 3) * 4;
        float acc[4][4] = {};
        for (int k0 = 0; k0 < 1024; k0 += 16) {
            float4 vw = *(const float4*)&w0[(bo + lr) * 1024 + k0 + lc];
            float4 vg = *(const float4*)&g0[(bo + lr) * 1024 + k0 + lc];
            float4 vp = *(const float4*)&p0[(bi + lr) * 1024 + k0 + lc];
            As[lr][lc + 0] = fabsf(vw.x - vg.x);
            As[lr][lc + 1] = fabsf(vw.y - vg.y);
            As[lr][lc + 2] = fabsf(vw.z - vg.z);
            As[lr][lc + 3] = fabsf(vw.w - vg.w);
            Bs[lr][lc + 0] = vp.x;
            Bs[lr][lc + 1] = vp.y;
            Bs[lr][lc + 2] = vp.z;
            Bs[lr][lc + 3] = vp.w;
            __syncthreads();
#pragma unroll
            for (int k = 0; k < 16; k++) {
                float av[4], bv[4];
#pragma unroll
                for (int r = 0; r < 4; r++) av[r] = As[ty * 4 + r][k];
#pragma unroll
                for (int c = 0; c < 4; c++) bv[c] = Bs[tx * 4 + c][k];
#pragma unroll
                for (int r = 0; r < 4; r++)
#pragma unroll
                    for (int c = 0; c < 4; c++) acc[r][c] += av[r] * bv[c];
            }
            __syncthreads();
        }
        float wg = wglobal_from_ent(ws_f[WS_ENT + 0], ws_f[WS_ENT + 1]);
#pragma unroll
        for (int r = 0; r < 4; r++) {
#pragma unroll
            for (int c = 0; c < 4; c++) {
                int o = bo + ty * 4 + r, i = bi + tx * 4 + c;
                float s0 = blend_factor(acc[r][c], wg);
                float v = w0[o * 1024 + i] * s0 + g0[o * 1024 + i] * (1.0f - s0);
                W0bb[o * 1024 + i] = (ushort_t)f2bf(v);
            }
        }
    }
}

// ---------------------------------------------------------------------------
// Main MFMA kernel: grid 1024, 256 threads (4 waves). Block = 64 rows x all
// 512 hidden cols, BK=32. Wave w covers cols w*128..+127 (8 n-tiles), all 64
// rows (4 m-tiles). acc[4][8] floatx4. x read exactly once (fp32->bf16 on the
// fly). B staged via global_load_lds(16B) with 2-way bank swizzle.
// Epilogue: relu(acc+b0)*W1b -> shuffle reduce -> LDS cross-wave -> out.
__global__ __launch_bounds__(256) void main_mfma(
    const float* __restrict__ x, const float* __restrict__ b0,
    const float* __restrict__ b1, const ushort_t* __restrict__ W0bb,
    const float* __restrict__ W1b, float* __restrict__ out) {
    __shared__ ushort_t As[64 * 40];   // [row][k] bf16, stride 40 (2-way free)
    __shared__ ushort_t Bs[512 * 32];  // [h][slot] bf16, swizzled slots
    __shared__ float red[4 * 64];

    int tid = threadIdx.x;
    int w = tid >> 6, l = tid & 63;
    int m_in = l & 15, kq = l >> 4;
    int row0 = blockIdx.x * 64;

    floatx4 acc[4][8];
    const floatx4 zero = {0.0f, 0.0f, 0.0f, 0.0f};
#pragma unroll
    for (int tm = 0; tm < 4; tm++)
#pragma unroll
        for (int tn = 0; tn < 8; tn++) acc[tm][tn] = zero;

    // A staging: thread t -> row t>>2 (0..63), k-chunk (t&3)*8
    int ar = tid >> 2, akc = (tid & 3) * 8;
    const float* xptr = x + (size_t)(row0 + ar) * 1024 + akc;
    ushort_t* awr = &As[ar * 40 + akc];

    // B staging: iter i: rows i*64 + w*16 + (l>>2); source chunk swizzled so
    // that LDS slot s holds chunk c = (s - (hl>>1)) & 3  (hl = h&15 = l>>2).
    int c_src = ((l & 3) - (l >> 3)) & 3;
    const ushort_t* bsrc = W0bb + (size_t)(w * 16 + (l >> 2)) * 1024 + c_src * 8;
    ushort_t* bdst = &Bs[w * 512];  // +i*2048; lane*16B implicit

    float4 xa = *(const float4*)(xptr);
    float4 xb = *(const float4*)(xptr + 4);

#pragma unroll 1
    for (int k0 = 0; k0 < 1024; k0 += 32) {
        // B: 32 KB tile via 8 async16 per thread (L2-resident source)
#pragma unroll
        for (int i = 0; i < 8; i++)
            async16(bsrc + i * 65536 + k0, bdst + i * 2048);
        // A: regs (prefetched) -> bf16 -> one ds_write_b128
        short8 s8;
        s8[0] = f2bf(xa.x); s8[1] = f2bf(xa.y); s8[2] = f2bf(xa.z); s8[3] = f2bf(xa.w);
        s8[4] = f2bf(xb.x); s8[5] = f2bf(xb.y); s8[6] = f2bf(xb.z); s8[7] = f2bf(xb.w);
        *(short8*)awr = s8;
        // prefetch next x chunk (drained at barrier; multi-block overlap covers)
        if (k0 + 32 < 1024) {
            xa = *(const float4*)(xptr + k0 + 32);
            xb = *(const float4*)(xptr + k0 + 36);
        }
        __syncthreads();
        short8 af[4], bfr[8];
#pragma unroll
        for (int tm = 0; tm < 4; tm++)
            af[tm] = *(const short8*)&As[(tm * 16 + m_in) * 40 + kq * 8];
        int s = (kq + (m_in >> 1)) & 3;
#pragma unroll
        for (int tn = 0; tn < 8; tn++) {
            int h = w * 128 + tn * 16 + m_in;
            bfr[tn] = *(const short8*)&Bs[h * 32 + s * 8];
        }
#pragma unroll
        for (int tm = 0; tm < 4; tm++)
#pragma unroll
            for (int tn = 0; tn < 8; tn++)
                acc[tm][tn] = __builtin_amdgcn_mfma_f32_16x16x32_bf16(
                    af[tm], bfr[tn], acc[tm][tn], 0, 0, 0);
        __syncthreads();
    }

    // ---- fused GEMV epilogue ----
    float b0v[8], w1v[8];
#pragma unroll
    for (int tn = 0; tn < 8; tn++) {
        int h = w * 128 + tn * 16 + m_in;
        b0v[tn] = b0[h];
        w1v[tn] = W1b[h];
    }
#pragma unroll
    for (int tm = 0; tm < 4; tm++) {
#pragma unroll
        for (int reg = 0; reg < 4; reg++) {
            float s = 0.0f;
#pragma unroll
            for (int tn = 0; tn < 8; tn++) {
                float y = acc[tm][tn][reg] + b0v[tn];
                y = fmaxf(y, 0.0f);
                s += y * w1v[tn];
            }
            s += __shfl_xor(s, 1);
            s += __shfl_xor(s, 2);
            s += __shfl_xor(s, 4);
            s += __shfl_xor(s, 8);
            if (m_in == 0) red[w * 64 + tm * 16 + kq * 4 + reg] = s;
        }
    }
    __syncthreads();
    if (tid < 64)
        out[row0 + tid] =
            red[tid] + red[64 + tid] + red[128 + tid] + red[192 + tid] + b1[0];
}

// ---------------------------------------------------------------------------
extern "C" void kernel_launch(void* const* d_in, const int* in_sizes, int n_in,
                              void* d_out, int out_size, void* d_ws, size_t ws_size,
                              hipStream_t stream) {
    const float* x = (const float*)d_in[0];
    const float* w0 = (const float*)d_in[1];
    const float* b0 = (const float*)d_in[2];
    const float* w1 = (const float*)d_in[3];
    const float* b1 = (const float*)d_in[4];
    const float* p0 = (const float*)d_in[5];
    const float* p1 = (const float*)d_in[6];
    const float* g0 = (const float*)d_in[7];
    const float* g1 = (const float*)d_in[8];
    float* out = (float*)d_out;
    unsigned* ws_u = (unsigned*)d_ws;
    float* ws_f = (float*)d_ws;
    ushort_t* W0bb = (ushort_t*)(ws_u + WS_W0B_WORD);
    float* W1b = ws_f + WS_W1B_WORD;

    void* args[] = {(void*)&w0, (void*)&g0, (void*)&w1, (void*)&g1,
                    (void*)&p0, (void*)&p1, (void*)&ws_u, (void*)&W0bb, (void*)&W1b};
    hipLaunchCooperativeKernel((void*)prep_kernel, dim3(130), dim3(256), args, 0, stream);
    main_mfma<<<1024, 256, 0, stream>>>(x, b0, b1, W0bb, W1b, out);
}